// Round 1
// baseline (909.491 us; speedup 1.0000x reference)
//
#include <hip/hip_runtime.h>
#include <hip/hip_bf16.h>

#define CDIM 128

typedef __attribute__((ext_vector_type(4))) float f32x4;
typedef __attribute__((ext_vector_type(8))) short bf16x8;

// f32 -> bf16 with round-to-nearest-even (bit trick, finite inputs)
__device__ __forceinline__ short f2bf(float f) {
    unsigned u = __float_as_uint(f);
    u += 0x7FFFu + ((u >> 16) & 1u);
    return (short)(u >> 16);
}

__global__ __launch_bounds__(256) void zero_out(float* __restrict__ o, long n4) {
    long i = (long)blockIdx.x * blockDim.x + threadIdx.x;
    const long stride = (long)gridDim.x * blockDim.x;
    const f32x4 z = {0.f, 0.f, 0.f, 0.f};
    for (; i < n4; i += stride) ((f32x4*)o)[i] = z;
}

__global__ __launch_bounds__(256) void sigmoid_inplace(float* __restrict__ o, long n4) {
    long i = (long)blockIdx.x * blockDim.x + threadIdx.x;
    const long stride = (long)gridDim.x * blockDim.x;
    for (; i < n4; i += stride) {
        f32x4 v = ((const f32x4*)o)[i];
#pragma unroll
        for (int j = 0; j < 4; ++j) v[j] = 1.0f / (1.0f + __expf(-v[j]));
        ((f32x4*)o)[i] = v;
    }
}

// Fused: for each edge e, out[cols[e]] += (x[rows[e]] @ W) * vals[e]
// Per wave: 16 edges as the M-dim of a 16x128 @ 128x128 MFMA tile.
// A frag (16x16x32 bf16): lane l holds A[row=l&15][k=8*(l>>4)+j]
// B frag: lane l holds B[k=8*(l>>4)+j][col=l&15]
// C/D:    lane l holds C[row=4*(l>>4)+r][col=l&15]  (verified layout, m89)
__global__ __launch_bounds__(256) void gather_mm_scatter(
    const float* __restrict__ x, const float* __restrict__ W,
    const int* __restrict__ rows, const int* __restrict__ cols,
    const float* __restrict__ vals, float* __restrict__ out, int nnz)
{
    // W^T in LDS as bf16, +8 short pad: row stride 272B -> 2-way bank alias (free)
    __shared__ short Wt[CDIM][CDIM + 8];
    for (int idx = threadIdx.x; idx < CDIM * CDIM; idx += 256) {
        int k = idx >> 7, n = idx & 127;
        Wt[n][k] = f2bf(W[idx]);   // W row-major [k][n] -> Wt[n][k]
    }
    __syncthreads();

    const int lane = threadIdx.x & 63;
    const int wid  = threadIdx.x >> 6;
    const int l15  = lane & 15;
    const int l4   = lane >> 4;          // 0..3
    const int nbatch = (nnz + 15) >> 4;

    for (int batch = blockIdx.x * 4 + wid; batch < nbatch; batch += gridDim.x * 4) {
        const int base = batch << 4;
        int e_a = base + l15; if (e_a >= nnz) e_a = nnz - 1;  // tail clamp (val=0 kills it)
        const int arow = rows[e_a];
        const float* __restrict__ xrow = x + (long)arow * CDIM + (l4 << 3);

        f32x4 acc[8];
#pragma unroll
        for (int nb = 0; nb < 8; ++nb) acc[nb] = (f32x4){0.f, 0.f, 0.f, 0.f};

#pragma unroll
        for (int kk = 0; kk < 4; ++kk) {
            f32x4 a0 = *(const f32x4*)(xrow + kk * 32);
            f32x4 a1 = *(const f32x4*)(xrow + kk * 32 + 4);
            union { bf16x8 v; short s[8]; } A;
#pragma unroll
            for (int j = 0; j < 4; ++j) { A.s[j] = f2bf(a0[j]); A.s[4 + j] = f2bf(a1[j]); }
#pragma unroll
            for (int nb = 0; nb < 8; ++nb) {
                bf16x8 b = *(const bf16x8*)&Wt[(nb << 4) + l15][(kk << 5) + (l4 << 3)];
                acc[nb] = __builtin_amdgcn_mfma_f32_16x16x32_bf16(A.v, b, acc[nb], 0, 0, 0);
            }
        }

#pragma unroll
        for (int r = 0; r < 4; ++r) {
            const int e = base + (l4 << 2) + r;
            int ccol = 0; float v = 0.f;
            if (e < nnz) { ccol = cols[e]; v = vals[e]; }
            float* orow = out + (long)ccol * CDIM + l15;
#pragma unroll
            for (int nb = 0; nb < 8; ++nb)
                atomicAdd(orow + (nb << 4), acc[nb][r] * v);
        }
    }
}

extern "C" void kernel_launch(void* const* d_in, const int* in_sizes, int n_in,
                              void* d_out, int out_size, void* d_ws, size_t ws_size,
                              hipStream_t stream) {
    const float* x0 = (const float*)d_in[0];
    const float* x1 = (const float*)d_in[1];
    const float* W1 = (const float*)d_in[3];
    const float* W2 = (const float*)d_in[4];
    const int*   b1r = (const int*)d_in[5];
    const int*   b1c = (const int*)d_in[6];
    const float* b1v = (const float*)d_in[7];
    const int*   b2r = (const int*)d_in[8];
    const int*   b2c = (const int*)d_in[9];
    const float* b2v = (const float*)d_in[10];
    const int nnz1 = in_sizes[5];
    const int nnz2 = in_sizes[8];
    const int n1   = in_sizes[1] / CDIM;   // 400000 edges (rank-1 cells)

    float* out  = (float*)d_out;
    float* out1 = out;
    float* out2 = out + (long)n1 * CDIM;
    const long n4 = (long)out_size / 4;

    zero_out<<<2048, 256, 0, stream>>>(out, n4);
    gather_mm_scatter<<<1024, 256, 0, stream>>>(x0, W1, b1r, b1c, b1v, out1, nnz1);
    gather_mm_scatter<<<1024, 256, 0, stream>>>(x1, W2, b2r, b2c, b2v, out2, nnz2);
    sigmoid_inplace<<<2048, 256, 0, stream>>>(out, n4);
}

// Round 2
// 561.931 us; speedup vs baseline: 1.6185x; 1.6185x over previous
//
#include <hip/hip_runtime.h>
#include <hip/hip_bf16.h>

#define CDIM 128
#define SCAN_CHUNK 2048   // elements per scan1 block (256 thr x 8)

typedef __attribute__((ext_vector_type(4))) float f32x4;
typedef __attribute__((ext_vector_type(8))) short bf16x8;

__device__ __forceinline__ short f2bf(float f) {
    unsigned u = __float_as_uint(f);
    u += 0x7FFFu + ((u >> 16) & 1u);
    return (short)(u >> 16);
}

// ---------------- CSR build ----------------

__global__ __launch_bounds__(256) void zero_ints(int* __restrict__ p, int n) {
    int i = blockIdx.x * 256 + threadIdx.x;
    for (; i < n; i += gridDim.x * 256) p[i] = 0;
}

__global__ __launch_bounds__(256) void hist(const int* __restrict__ cols, int nnz,
                                            int dest_base, int* __restrict__ counts) {
    int e = blockIdx.x * 256 + threadIdx.x;
    for (; e < nnz; e += gridDim.x * 256)
        atomicAdd(&counts[dest_base + cols[e]], 1);
}

// chunk-local exclusive scan; writes per-chunk total to sums[chunk]
__global__ __launch_bounds__(256) void scan1(const int* __restrict__ in, int* __restrict__ out,
                                             int* __restrict__ sums, int n) {
    __shared__ int wtot[4];
    const int t = threadIdx.x;
    const int base = blockIdx.x * SCAN_CHUNK + t * 8;
    int v[8]; int s = 0;
#pragma unroll
    for (int j = 0; j < 8; ++j) {
        int c = (base + j < n) ? in[base + j] : 0;
        v[j] = s; s += c;
    }
    const int lane = t & 63, w = t >> 6;
    int inc = s;
#pragma unroll
    for (int d = 1; d < 64; d <<= 1) {
        int o = __shfl_up(inc, d);
        if (lane >= d) inc += o;
    }
    if (lane == 63) wtot[w] = inc;
    __syncthreads();
    int off = inc - s;  // exclusive within wave
    for (int i = 0; i < w; ++i) off += wtot[i];
#pragma unroll
    for (int j = 0; j < 8; ++j)
        if (base + j < n) out[base + j] = v[j] + off;
    if (t == 255) sums[blockIdx.x] = off + s;
}

// single-block scan of chunk sums -> exclusive chunk offsets; writes grand total to row_ptr[n]
__global__ __launch_bounds__(512) void scan2(int* __restrict__ sums, int* __restrict__ row_ptr,
                                             int nchunks, int n) {
    __shared__ int sm[512];
    const int t = threadIdx.x;
    const int v = (t < nchunks) ? sums[t] : 0;
    sm[t] = v;
    __syncthreads();
    for (int d = 1; d < 512; d <<= 1) {
        int add = (t >= d) ? sm[t - d] : 0;
        __syncthreads();
        sm[t] += add;
        __syncthreads();
    }
    if (t < nchunks) sums[t] = sm[t] - v;          // exclusive offset
    if (t == nchunks - 1) row_ptr[n] = sm[t];      // total nnz
}

// finalize row_ptr and init cursor
__global__ __launch_bounds__(256) void scan3(int* __restrict__ row_ptr, const int* __restrict__ sums,
                                             int* __restrict__ cursor, int n) {
    int i = blockIdx.x * 256 + threadIdx.x;
    for (; i < n; i += gridDim.x * 256) {
        int val = row_ptr[i] + sums[i / SCAN_CHUNK];
        row_ptr[i] = val;
        cursor[i] = val;
    }
}

__global__ __launch_bounds__(256) void scatter_csr(const int* __restrict__ rows, const int* __restrict__ cols,
                                                   const float* __restrict__ vals, int nnz, int dest_base,
                                                   int* __restrict__ cursor, int* __restrict__ csr_src,
                                                   float* __restrict__ csr_val) {
    int e = blockIdx.x * 256 + threadIdx.x;
    for (; e < nnz; e += gridDim.x * 256) {
        int d = dest_base + cols[e];
        int p = atomicAdd(&cursor[d], 1);
        csr_src[p] = rows[e];
        csr_val[p] = vals[e];
    }
}

// ---------------- fused aggregate -> GEMM -> sigmoid ----------------
// Per wave: one tile of 16 dest rows. agg[r] = sum_{e in seg(r)} val_e * x[src_e]  (f32),
// then (16x128) @ W (128x128) via 16x16x32 bf16 MFMA, sigmoid, store once.
// A frag: lane l holds A[row=l&15][k = kk*32 + 8*(l>>4)+j]
// B frag: lane l holds B[k][col=l&15]   (from Wt[col][k])
// C/D:    lane l holds C[row=4*(l>>4)+ri][col=l&15]
__global__ __launch_bounds__(256) void fused_agg_mm(
    const float* __restrict__ x, const float* __restrict__ W,
    const int* __restrict__ row_ptr, const int* __restrict__ csr_src,
    const float* __restrict__ csr_val, float* __restrict__ out, int nrows)
{
    __shared__ short Wt[CDIM][CDIM + 8];
    for (int idx = threadIdx.x; idx < CDIM * CDIM; idx += 256) {
        int k = idx >> 7, n = idx & 127;
        Wt[n][k] = f2bf(W[idx]);
    }
    __syncthreads();

    const int lane = threadIdx.x & 63;
    const int wid  = threadIdx.x >> 6;
    const int l15  = lane & 15;
    const int l4   = lane >> 4;
    const int ntiles = nrows >> 4;   // nrows is a multiple of 16 (400000, 300000)

    for (int tile = blockIdx.x * 4 + wid; tile < ntiles; tile += gridDim.x * 4) {
        const int rbase = tile << 4;
        const int r = rbase + l15;
        const int beg = row_ptr[r];
        const int end = row_ptr[r + 1];

        float acc[4][8];
#pragma unroll
        for (int kk = 0; kk < 4; ++kk)
#pragma unroll
            for (int j = 0; j < 8; ++j) acc[kk][j] = 0.f;

        for (int i = beg; i < end; ++i) {
            const int src = csr_src[i];
            const float v = csr_val[i];
            const float* __restrict__ xr = x + (long)src * CDIM + (l4 << 3);
#pragma unroll
            for (int kk = 0; kk < 4; ++kk) {
                f32x4 a0 = *(const f32x4*)(xr + kk * 32);
                f32x4 a1 = *(const f32x4*)(xr + kk * 32 + 4);
#pragma unroll
                for (int j = 0; j < 4; ++j) {
                    acc[kk][j]     += v * a0[j];
                    acc[kk][4 + j] += v * a1[j];
                }
            }
        }

        f32x4 c[8];
#pragma unroll
        for (int nb = 0; nb < 8; ++nb) c[nb] = (f32x4){0.f, 0.f, 0.f, 0.f};

#pragma unroll
        for (int kk = 0; kk < 4; ++kk) {
            union { bf16x8 v; short s[8]; } A;
#pragma unroll
            for (int j = 0; j < 8; ++j) A.s[j] = f2bf(acc[kk][j]);
#pragma unroll
            for (int nb = 0; nb < 8; ++nb) {
                bf16x8 b = *(const bf16x8*)&Wt[(nb << 4) + l15][(kk << 5) + (l4 << 3)];
                c[nb] = __builtin_amdgcn_mfma_f32_16x16x32_bf16(A.v, b, c[nb], 0, 0, 0);
            }
        }

#pragma unroll
        for (int nb = 0; nb < 8; ++nb) {
#pragma unroll
            for (int ri = 0; ri < 4; ++ri) {
                float y = 1.0f / (1.0f + __expf(-c[nb][ri]));
                out[(long)(rbase + (l4 << 2) + ri) * CDIM + (nb << 4) + l15] = y;
            }
        }
    }
}

// ---------------- launch ----------------

extern "C" void kernel_launch(void* const* d_in, const int* in_sizes, int n_in,
                              void* d_out, int out_size, void* d_ws, size_t ws_size,
                              hipStream_t stream) {
    const float* x0 = (const float*)d_in[0];
    const float* x1 = (const float*)d_in[1];
    const float* W1 = (const float*)d_in[3];
    const float* W2 = (const float*)d_in[4];
    const int*   b1r = (const int*)d_in[5];
    const int*   b1c = (const int*)d_in[6];
    const float* b1v = (const float*)d_in[7];
    const int*   b2r = (const int*)d_in[8];
    const int*   b2c = (const int*)d_in[9];
    const float* b2v = (const float*)d_in[10];
    const int nnz1 = in_sizes[5];
    const int nnz2 = in_sizes[8];
    const int n1   = in_sizes[1] / CDIM;   // 400000
    const int n2   = in_sizes[2] / CDIM;   // 300000
    const int N    = n1 + n2;              // combined dest space
    const int nnzT = nnz1 + nnz2;

    // workspace carve-up (all 4-byte elements)
    int* counts  = (int*)d_ws;             // N
    int* row_ptr = counts + N;             // N+1
    int* cursor  = row_ptr + N + 1;        // N
    int* sums    = cursor + N;             // <=512 chunks
    int* csr_src = sums + 512;             // nnzT
    float* csr_val = (float*)(csr_src + nnzT); // nnzT

    float* out1 = (float*)d_out;
    float* out2 = out1 + (long)n1 * CDIM;

    const int nchunks = (N + SCAN_CHUNK - 1) / SCAN_CHUNK;

    zero_ints<<<1024, 256, 0, stream>>>(counts, N);
    hist<<<1024, 256, 0, stream>>>(b1c, nnz1, 0, counts);
    hist<<<1024, 256, 0, stream>>>(b2c, nnz2, n1, counts);
    scan1<<<nchunks, 256, 0, stream>>>(counts, row_ptr, sums, N);
    scan2<<<1, 512, 0, stream>>>(sums, row_ptr, nchunks, N);
    scan3<<<1024, 256, 0, stream>>>(row_ptr, sums, cursor, N);
    scatter_csr<<<1024, 256, 0, stream>>>(b1r, b1c, b1v, nnz1, 0, cursor, csr_src, csr_val);
    scatter_csr<<<1024, 256, 0, stream>>>(b2r, b2c, b2v, nnz2, n1, cursor, csr_src, csr_val);

    fused_agg_mm<<<(n1 >> 4) / 4, 256, 0, stream>>>(x0, W1, row_ptr,      csr_src, csr_val, out1, n1);
    fused_agg_mm<<<((n2 >> 4) + 3) / 4, 256, 0, stream>>>(x1, W2, row_ptr + n1, csr_src, csr_val, out2, n2);
}

// Round 3
// 522.081 us; speedup vs baseline: 1.7421x; 1.0763x over previous
//
#include <hip/hip_runtime.h>
#include <hip/hip_bf16.h>

#define CDIM 128
#define SCAN_CHUNK 2048   // elements per scan1 block (256 thr x 8)

typedef __attribute__((ext_vector_type(4))) float f32x4;
typedef __attribute__((ext_vector_type(8))) short bf16x8;
typedef __attribute__((ext_vector_type(4))) short bf16x4;

__device__ __forceinline__ short f2bf(float f) {
    unsigned u = __float_as_uint(f);
    u += 0x7FFFu + ((u >> 16) & 1u);
    return (short)(u >> 16);
}

// ---------------- CSR build ----------------

__global__ __launch_bounds__(256) void zero_ints(int* __restrict__ p, int n) {
    int i = blockIdx.x * 256 + threadIdx.x;
    for (; i < n; i += gridDim.x * 256) p[i] = 0;
}

__global__ __launch_bounds__(256) void hist(const int* __restrict__ cols, int nnz,
                                            int dest_base, int* __restrict__ counts) {
    int e = blockIdx.x * 256 + threadIdx.x;
    for (; e < nnz; e += gridDim.x * 256)
        atomicAdd(&counts[dest_base + cols[e]], 1);
}

__global__ __launch_bounds__(256) void scan1(const int* __restrict__ in, int* __restrict__ out,
                                             int* __restrict__ sums, int n) {
    __shared__ int wtot[4];
    const int t = threadIdx.x;
    const int base = blockIdx.x * SCAN_CHUNK + t * 8;
    int v[8]; int s = 0;
#pragma unroll
    for (int j = 0; j < 8; ++j) {
        int c = (base + j < n) ? in[base + j] : 0;
        v[j] = s; s += c;
    }
    const int lane = t & 63, w = t >> 6;
    int inc = s;
#pragma unroll
    for (int d = 1; d < 64; d <<= 1) {
        int o = __shfl_up(inc, d);
        if (lane >= d) inc += o;
    }
    if (lane == 63) wtot[w] = inc;
    __syncthreads();
    int off = inc - s;
    for (int i = 0; i < w; ++i) off += wtot[i];
#pragma unroll
    for (int j = 0; j < 8; ++j)
        if (base + j < n) out[base + j] = v[j] + off;
    if (t == 255) sums[blockIdx.x] = off + s;
}

__global__ __launch_bounds__(512) void scan2(int* __restrict__ sums, int* __restrict__ row_ptr,
                                             int nchunks, int n) {
    __shared__ int sm[512];
    const int t = threadIdx.x;
    const int v = (t < nchunks) ? sums[t] : 0;
    sm[t] = v;
    __syncthreads();
    for (int d = 1; d < 512; d <<= 1) {
        int add = (t >= d) ? sm[t - d] : 0;
        __syncthreads();
        sm[t] += add;
        __syncthreads();
    }
    if (t < nchunks) sums[t] = sm[t] - v;
    if (t == nchunks - 1) row_ptr[n] = sm[t];
}

__global__ __launch_bounds__(256) void scan3(int* __restrict__ row_ptr, const int* __restrict__ sums,
                                             int* __restrict__ cursor, int n) {
    int i = blockIdx.x * 256 + threadIdx.x;
    for (; i < n; i += gridDim.x * 256) {
        int val = row_ptr[i] + sums[i / SCAN_CHUNK];
        row_ptr[i] = val;
        cursor[i] = val;
    }
}

__global__ __launch_bounds__(256) void scatter_csr(const int* __restrict__ rows, const int* __restrict__ cols,
                                                   const float* __restrict__ vals, int nnz, int dest_base,
                                                   int* __restrict__ cursor,
                                                   unsigned long long* __restrict__ csr) {
    int e = blockIdx.x * 256 + threadIdx.x;
    for (; e < nnz; e += gridDim.x * 256) {
        int d = dest_base + cols[e];
        int p = atomicAdd(&cursor[d], 1);
        csr[p] = ((unsigned long long)__float_as_uint(vals[e]) << 32) | (unsigned)rows[e];
    }
}

// ---------------- dense GEMM: h = bf16(x @ W) ----------------
// Swapped operands: D = A(=W^T frag) * B(=x^T frag) -> lane's 4 regs are 4
// consecutive h-columns of one row -> packed 8B stores.
// W staged fragment-packed in LDS: lane-linear 16B slots, zero bank conflicts.
__global__ __launch_bounds__(256) void gemm_h(
    const float* __restrict__ x, const float* __restrict__ W,
    short* __restrict__ h, int nrows)
{
    __shared__ short Bfrag[4][8][64][8];   // [kk][nb][lane][j]  = 32 KB
    for (int slot = threadIdx.x; slot < 2048; slot += 256) {
        const int lane = slot & 63, nb = (slot >> 6) & 7, kk = slot >> 9;
        const int n  = nb * 16 + (lane & 15);
        const int k0 = kk * 32 + (lane >> 4) * 8;
        union { bf16x8 v; short s[8]; } f;
#pragma unroll
        for (int j = 0; j < 8; ++j) f.s[j] = f2bf(W[(k0 + j) * CDIM + n]);
        *(bf16x8*)&Bfrag[kk][nb][lane][0] = f.v;
    }
    __syncthreads();

    const int lane = threadIdx.x & 63;
    const int wid  = threadIdx.x >> 6;
    const int l15  = lane & 15;
    const int l4   = lane >> 4;
    const int ntiles = nrows >> 4;

    for (int tile = blockIdx.x * 4 + wid; tile < ntiles; tile += gridDim.x * 4) {
        const int rbase = tile << 4;
        const int row = rbase + l15;
        const float* __restrict__ xr = x + (long)row * CDIM + (l4 << 3);

        union { bf16x8 v; short s[8]; } X[4];
#pragma unroll
        for (int kk = 0; kk < 4; ++kk) {
            f32x4 a0 = *(const f32x4*)(xr + kk * 32);
            f32x4 a1 = *(const f32x4*)(xr + kk * 32 + 4);
#pragma unroll
            for (int j = 0; j < 4; ++j) { X[kk].s[j] = f2bf(a0[j]); X[kk].s[4 + j] = f2bf(a1[j]); }
        }

        f32x4 c[8];
#pragma unroll
        for (int nb = 0; nb < 8; ++nb) c[nb] = (f32x4){0.f, 0.f, 0.f, 0.f};
#pragma unroll
        for (int kk = 0; kk < 4; ++kk)
#pragma unroll
            for (int nb = 0; nb < 8; ++nb)
                c[nb] = __builtin_amdgcn_mfma_f32_16x16x32_bf16(
                            *(const bf16x8*)&Bfrag[kk][nb][lane][0], X[kk].v, c[nb], 0, 0, 0);

        // c[nb][ri] = h[row][nb*16 + l4*4 + ri]
        short* __restrict__ hr = h + (long)row * CDIM + (l4 << 2);
#pragma unroll
        for (int nb = 0; nb < 8; ++nb) {
            bf16x4 p;
#pragma unroll
            for (int ri = 0; ri < 4; ++ri) p[ri] = f2bf(c[nb][ri]);
            *(bf16x4*)(hr + (nb << 4)) = p;
        }
    }
}

// ---------------- gather-aggregate-sigmoid ----------------
// 16 lanes per dest row (16B bf16 chunk each), 4 rows per wave, 16 rows/block.
__global__ __launch_bounds__(256) void agg_sigmoid(
    const short* __restrict__ h, const int* __restrict__ row_ptr,
    const unsigned long long* __restrict__ csr, float* __restrict__ out, int nrows)
{
    const int lane = threadIdx.x & 63;
    const int wid  = threadIdx.x >> 6;
    const int g    = lane >> 4;     // row slot within wave
    const int t16  = lane & 15;
    const int r = blockIdx.x * 16 + wid * 4 + g;
    const int beg = row_ptr[r];
    const int end = row_ptr[r + 1];

    float acc[8] = {0.f, 0.f, 0.f, 0.f, 0.f, 0.f, 0.f, 0.f};
    for (int i = beg; i < end; ++i) {
        const unsigned long long pv = csr[i];
        const int   src = (int)(unsigned)pv;
        const float val = __uint_as_float((unsigned)(pv >> 32));
        union { bf16x8 v; unsigned u[4]; } H;
        H.v = *(const bf16x8*)(h + (long)src * CDIM + (t16 << 3));
#pragma unroll
        for (int d = 0; d < 4; ++d) {
            float lo = __uint_as_float(H.u[d] << 16);
            float hi = __uint_as_float(H.u[d] & 0xffff0000u);
            acc[2 * d]     += val * lo;
            acc[2 * d + 1] += val * hi;
        }
    }

    f32x4 o0, o1;
#pragma unroll
    for (int j = 0; j < 4; ++j) {
        o0[j] = 1.0f / (1.0f + __expf(-acc[j]));
        o1[j] = 1.0f / (1.0f + __expf(-acc[4 + j]));
    }
    float* __restrict__ orow = out + (long)r * CDIM + (t16 << 3);
    *(f32x4*)orow = o0;
    *(f32x4*)(orow + 4) = o1;
}

// ---------------- launch ----------------

extern "C" void kernel_launch(void* const* d_in, const int* in_sizes, int n_in,
                              void* d_out, int out_size, void* d_ws, size_t ws_size,
                              hipStream_t stream) {
    const float* x0 = (const float*)d_in[0];
    const float* x1 = (const float*)d_in[1];
    const float* W1 = (const float*)d_in[3];
    const float* W2 = (const float*)d_in[4];
    const int*   b1r = (const int*)d_in[5];
    const int*   b1c = (const int*)d_in[6];
    const float* b1v = (const float*)d_in[7];
    const int*   b2r = (const int*)d_in[8];
    const int*   b2c = (const int*)d_in[9];
    const float* b2v = (const float*)d_in[10];
    const int nnz1 = in_sizes[5];
    const int nnz2 = in_sizes[8];
    const int n0   = in_sizes[0] / CDIM;   // 100000 (x0 rows)
    const int n1   = in_sizes[1] / CDIM;   // 400000 (x1 rows = out1 rows)
    const int n2   = in_sizes[2] / CDIM;   // 300000 (out2 rows)
    const int N    = n1 + n2;              // combined dest space
    const int nnzT = nnz1 + nnz2;

    // workspace carve-up
    int* counts  = (int*)d_ws;             // N
    int* row_ptr = counts + N;             // N+1
    int* cursor  = row_ptr + N + 1;        // N
    int* sums    = cursor + N;             // 512
    size_t iofs = (size_t)3 * N + 513;
    iofs = (iofs + 1) & ~(size_t)1;        // 8B align
    unsigned long long* csr = (unsigned long long*)((int*)d_ws + iofs);  // nnzT
    short* h0 = (short*)(csr + nnzT);                 // n0*128 bf16
    short* h1 = h0 + (size_t)n0 * CDIM;               // n1*128 bf16

    float* out1 = (float*)d_out;
    float* out2 = out1 + (long)n1 * CDIM;

    const int nchunks = (N + SCAN_CHUNK - 1) / SCAN_CHUNK;

    zero_ints<<<1024, 256, 0, stream>>>(counts, N);
    hist<<<1024, 256, 0, stream>>>(b1c, nnz1, 0, counts);
    hist<<<1024, 256, 0, stream>>>(b2c, nnz2, n1, counts);
    scan1<<<nchunks, 256, 0, stream>>>(counts, row_ptr, sums, N);
    scan2<<<1, 512, 0, stream>>>(sums, row_ptr, nchunks, N);
    scan3<<<1024, 256, 0, stream>>>(row_ptr, sums, cursor, N);
    scatter_csr<<<1024, 256, 0, stream>>>(b1r, b1c, b1v, nnz1, 0, cursor, csr);
    scatter_csr<<<1024, 256, 0, stream>>>(b2r, b2c, b2v, nnz2, n1, cursor, csr);

    int g0 = ((n0 >> 4) + 3) / 4; if (g0 > 2048) g0 = 2048;
    int g1 = ((n1 >> 4) + 3) / 4; if (g1 > 2048) g1 = 2048;
    gemm_h<<<g0, 256, 0, stream>>>(x0, W1, h0, n0);
    gemm_h<<<g1, 256, 0, stream>>>(x1, W2, h1, n1);

    // agg2 first: h1 (102 MB) is freshest in L3
    agg_sigmoid<<<n2 >> 4, 256, 0, stream>>>(h1, row_ptr + n1, csr, out2, n2);
    agg_sigmoid<<<n1 >> 4, 256, 0, stream>>>(h0, row_ptr,      csr, out1, n1);
}